// Round 5
// baseline (659.188 us; speedup 1.0000x reference)
//
#include <hip/hip_runtime.h>
#include <math.h>

// Problem: B=64, S=2048, H=1024. Single-query attention + concat.
// out[b, 0:H]  = h_n[b]
// out[b, H:2H] = softmax_s(h_n[b]·enc[b,s,:]) @ enc[b,:,:]
//
// Timed window per iteration = 2.1GB ws poison-fill (~335us, fixed, runs
// exclusively at 6.4 TB/s) + partial (~300us = 537MB @ 1.8 TB/s) + final
// (~6us). The partial is 3.5x under the BW the fill proves. Dead theories:
// address phase-lock (r1/r3: +-10%), per-wave outstanding bytes (r4: null).
//
// v5: make each WAVE a linear streamer, like the fill's writers:
//  - NCHUNK=32 -> 2048 blocks -> 8 blocks/CU (2x wave residency).
//  - wave owns 16 CONSECUTIVE rows (64KB), walks them sequentially
//    (4KB stride) instead of striding 16KB (rows w, w+4, ...). DRAM
//    row-buffer locality + sequential-stream behavior.
//  - per-wave start rotation WITHIN the run (wrap once) decorrelates
//    low addr bits across the 8192 streams without breaking linearity.
//  - single-row iterations keep VGPR ~80 so the residency gain survives.
//  - keep nontemporal loads + lazy rescale (r3/r4, proven correct).

#define BB 64
#define SS 2048
#define HH 1024
#define NCHUNK 32              // S-chunks per batch -> 64*32 = 2048 blocks
#define SCHUNK (SS / NCHUNK)   // 64 rows per block
#define NWAVE 4                // 256 threads
#define RUN (SCHUNK / NWAVE)   // 16 consecutive rows per wave

typedef float fvec4 __attribute__((ext_vector_type(4)));

// ws layout:
//   [0 .. B*NCHUNK*H)              : partial ctx accumulators (8.4 MB)
//   [B*NCHUNK*H .. +B*NCHUNK*2)    : (m, l) pairs per partial
#define WS_ML_OFF ((size_t)BB * NCHUNK * HH)

__global__ __launch_bounds__(256) void attn_partial_kernel(
    const float* __restrict__ enc, const float* __restrict__ hn,
    float* __restrict__ ws)
{
    const int blk   = blockIdx.x;          // b * NCHUNK + chunk
    const int b     = blk >> 5;            // / NCHUNK
    const int chunk = blk & (NCHUNK - 1);
    const int tid   = threadIdx.x;
    const int wave  = tid >> 6;
    const int lane  = tid & 63;

    // Preload this lane's 16 h_n elements
    const fvec4* hn4 = (const fvec4*)(hn + (size_t)b * HH);
    fvec4 h4[4];
#pragma unroll
    for (int j = 0; j < 4; ++j) h4[j] = hn4[j * 64 + lane];

    const fvec4* enc4 = (const fvec4*)(enc + (size_t)b * SS * HH);

    float m = -INFINITY;
    float l = 0.0f;
    fvec4 acc[4];
#pragma unroll
    for (int j = 0; j < 4; ++j) acc[j] = (fvec4)(0.f, 0.f, 0.f, 0.f);

    const int rowbase = chunk * SCHUNK + wave * RUN;  // wave's 64KB run
    const int start   = (blk * 53 + wave * 29) & (RUN - 1);

    for (int i = 0; i < RUN; ++i) {
        const int r = rowbase + ((start + i) & (RUN - 1));
        const fvec4* row = enc4 + (size_t)r * (HH / 4);
        fvec4 e[4];
#pragma unroll
        for (int j = 0; j < 4; ++j)
            e[j] = __builtin_nontemporal_load(&row[j * 64 + lane]);

        float d = 0.0f;
#pragma unroll
        for (int j = 0; j < 4; ++j) {
            d += e[j].x * h4[j].x + e[j].y * h4[j].y
               + e[j].z * h4[j].z + e[j].w * h4[j].w;
        }
        // wave-64 butterfly reduce (d becomes wave-uniform)
#pragma unroll
        for (int off = 32; off > 0; off >>= 1)
            d += __shfl_xor(d, off, 64);

        // lazy online softmax: branch is wave-uniform (d uniform)
        if (d <= m) {          // common: max unchanged, no acc rescale
            const float p = __expf(d - m);
            l += p;
#pragma unroll
            for (int j = 0; j < 4; ++j) {
                acc[j].x = fmaf(p, e[j].x, acc[j].x);
                acc[j].y = fmaf(p, e[j].y, acc[j].y);
                acc[j].z = fmaf(p, e[j].z, acc[j].z);
                acc[j].w = fmaf(p, e[j].w, acc[j].w);
            }
        } else {               // max grew: rescale (p = exp(d-d) = 1)
            const float sc = __expf(m - d);   // first iter: exp(-inf)=0
            l = fmaf(l, sc, 1.0f);
            m = d;
#pragma unroll
            for (int j = 0; j < 4; ++j) {
                acc[j].x = fmaf(acc[j].x, sc, e[j].x);
                acc[j].y = fmaf(acc[j].y, sc, e[j].y);
                acc[j].z = fmaf(acc[j].z, sc, e[j].z);
                acc[j].w = fmaf(acc[j].w, sc, e[j].w);
            }
        }
    }

    // ---- combine 4 wave-partials within the block via LDS ----
    __shared__ float s_m[NWAVE];
    __shared__ float s_l[NWAVE];
    __shared__ float s_acc[NWAVE][HH];     // 16 KB

#pragma unroll
    for (int j = 0; j < 4; ++j)
        ((fvec4*)s_acc[wave])[j * 64 + lane] = acc[j];
    if (lane == 0) { s_m[wave] = m; s_l[wave] = l; }
    __syncthreads();

    float M = fmaxf(fmaxf(s_m[0], s_m[1]), fmaxf(s_m[2], s_m[3]));
    float sc2[NWAVE];
    float L = 0.0f;
#pragma unroll
    for (int w = 0; w < NWAVE; ++w) {
        sc2[w] = __expf(s_m[w] - M);
        L += s_l[w] * sc2[w];
    }

    fvec4 ctx = (fvec4)(0.f, 0.f, 0.f, 0.f);
#pragma unroll
    for (int w = 0; w < NWAVE; ++w) {
        fvec4 a = ((const fvec4*)s_acc[w])[tid];
        ctx.x += sc2[w] * a.x;  ctx.y += sc2[w] * a.y;
        ctx.z += sc2[w] * a.z;  ctx.w += sc2[w] * a.w;
    }
    ((fvec4*)(ws + (size_t)blk * HH))[tid] = ctx;
    if (tid == 0) {
        ws[WS_ML_OFF + (size_t)blk * 2 + 0] = M;
        ws[WS_ML_OFF + (size_t)blk * 2 + 1] = L;
    }
}

__global__ __launch_bounds__(256) void attn_final_kernel(
    const float* __restrict__ hn, const float* __restrict__ ws,
    float* __restrict__ out)
{
    const int b   = blockIdx.x;
    const int tid = threadIdx.x;
    const float* ml = ws + WS_ML_OFF + (size_t)b * NCHUNK * 2;

    float M = -INFINITY;
#pragma unroll
    for (int c = 0; c < NCHUNK; ++c) M = fmaxf(M, ml[c * 2]);

    float sc[NCHUNK];
    float T = 0.0f;
#pragma unroll
    for (int c = 0; c < NCHUNK; ++c) {
        sc[c] = __expf(ml[c * 2] - M);
        T += sc[c] * ml[c * 2 + 1];
    }
    const float invT = 1.0f / T;

    fvec4 ctx = (fvec4)(0.f, 0.f, 0.f, 0.f);
#pragma unroll
    for (int c = 0; c < NCHUNK; ++c) {
        fvec4 a = ((const fvec4*)(ws + (size_t)(b * NCHUNK + c) * HH))[tid];
        ctx.x += sc[c] * a.x;  ctx.y += sc[c] * a.y;
        ctx.z += sc[c] * a.z;  ctx.w += sc[c] * a.w;
    }
    ctx.x *= invT; ctx.y *= invT; ctx.z *= invT; ctx.w *= invT;

    const fvec4 dec = ((const fvec4*)(hn + (size_t)b * HH))[tid];
    fvec4* o = (fvec4*)(out + (size_t)b * 2 * HH);
    o[tid]            = dec;   // dec_output half
    o[tid + (HH / 4)] = ctx;   // context half
}

extern "C" void kernel_launch(void* const* d_in, const int* in_sizes, int n_in,
                              void* d_out, int out_size, void* d_ws, size_t ws_size,
                              hipStream_t stream) {
    const float* enc = (const float*)d_in[0];   // (B, S, H) fp32
    const float* hn  = (const float*)d_in[1];   // (B, H) fp32
    float* out = (float*)d_out;                 // (B, 1, 2H) fp32
    float* ws  = (float*)d_ws;

    attn_partial_kernel<<<dim3(BB * NCHUNK), dim3(256), 0, stream>>>(enc, hn, ws);
    attn_final_kernel<<<dim3(BB), dim3(256), 0, stream>>>(hn, ws, out);
}